// Round 21
// baseline (364.819 us; speedup 1.0000x reference)
//
#include <hip/hip_runtime.h>
#include <hip/hip_bf16.h>

// 2-layer LSTM (H=32, T=512, I=1) + FC(1) + ReLU, fused, SELF-ALIGNED
// single-wave layers (R18 structure) + SOURCE-STAGED ILP activation.
// R18's post-mortem: issue ~600 cyc/step but wall 1820 -- the compiler
// serialized the 8 CELL chains (48 dependent trans ops x ~25cy = the
// ~1220-cyc stall), discarding the design's ILP-8. This version stages
// the activation work explicitly: all 32 exp2 -> products -> 8 rcp ->
// 8 fma(cv) -> 8 exp2 -> 8 rcp -> 8 mul. Every stage is 8-32 independent
// ops, so even strict source-order issue keeps the quarter-rate trans
// pipe full; only ~6 stage boundaries pay latency.
// Structure (verified in R18): tile t row rho = gate(rho&3) of unit
// 8*(rho>>2)+t => lane (m,col) holds (i,f,g,o) of units 8m..8m+7 of batch
// col = its own next-step B-fragment. Recurrence closes IN-REGISTER (no
// LDS/swizzle/barrier inside a layer). w0 = layer 0, w1 = layer 1 lagging
// 4..7 steps behind an 8-deep LDS ring of h0; one barrier per 4 steps.
// Zero gate select; bias (+x for L0) in MFMA C-in. Grid 256 x 128.

typedef __attribute__((ext_vector_type(8))) short bf16x8;
typedef __attribute__((ext_vector_type(4))) float f32x4;
typedef __attribute__((ext_vector_type(4))) int   i32x4;

#define HID 32
#define SEQ 512
#define L2E 1.4426950408889634f
#define LSTR 20   // ring row stride in dwords (16 used + 4 pad)

static __device__ __forceinline__ float fexp2(float x){ return __builtin_amdgcn_exp2f(x); }
static __device__ __forceinline__ float frcp (float x){ return __builtin_amdgcn_rcpf(x); }
static __device__ __forceinline__ short f2bf(float f){
  unsigned u = __builtin_bit_cast(unsigned, f);
  u = (u + 0x7fffu + ((u >> 16) & 1u)) >> 16;
  return (short)u;
}

// staged 8-cell LSTM update: A[t][r] = pre-scaled gate r of unit 8m+t.
// (i,f,o scaled by -log2e, g by +2*log2e; biases already in A via C-in.)
// Updates cv[8], hh[8] of the enclosing scope.
#define SCELL8(A) do {                                                        \
  float I8[8], F8[8], G8[8], O8[8];                                           \
  _Pragma("unroll")                                                           \
  for (int t = 0; t < 8; ++t) {   /* stage 1: 32 independent exp2 */          \
    I8[t] = fexp2(A[t][0]); F8[t] = fexp2(A[t][1]);                           \
    G8[t] = fexp2(A[t][2]); O8[t] = fexp2(A[t][3]);                           \
  }                                                                           \
  float P1[8], PC[8], RA[8];                                                  \
  _Pragma("unroll")                                                           \
  for (int t = 0; t < 8; ++t) {   /* stage 2: VALU products */                \
    PC[t] = 1.f + F8[t];                                                      \
    P1[t] = (1.f + I8[t]) * (1.f + G8[t]);                                    \
  }                                                                           \
  _Pragma("unroll")                                                           \
  for (int t = 0; t < 8; ++t) RA[t] = frcp(PC[t] * P1[t]);  /* 8 indep rcp */ \
  _Pragma("unroll")                                                           \
  for (int t = 0; t < 8; ++t)     /* stage 4: cell update */                  \
    cv[t] = fmaf(P1[t] * RA[t], cv[t], (G8[t] - 1.f) * (PC[t] * RA[t]));      \
  float C2[8];                                                                \
  _Pragma("unroll")                                                           \
  for (int t = 0; t < 8; ++t) C2[t] = fexp2(cv[t] * (2.f * L2E));             \
  float R2[8];                                                                \
  _Pragma("unroll")                                                           \
  for (int t = 0; t < 8; ++t) R2[t] = frcp((1.f + O8[t]) * (1.f + C2[t]));    \
  _Pragma("unroll")                                                           \
  for (int t = 0; t < 8; ++t) hh[t] = (C2[t] - 1.f) * R2[t];                  \
} while (0)

__global__ __launch_bounds__(128, 1) void lstm2_sa2_kernel(
    const float* __restrict__ x,
    const float* __restrict__ Wih0, const float* __restrict__ Whh0,
    const float* __restrict__ bih0, const float* __restrict__ bhh0,
    const float* __restrict__ Wih1, const float* __restrict__ Whh1,
    const float* __restrict__ bih1, const float* __restrict__ bhh1,
    const float* __restrict__ Wfc, const float* __restrict__ bfc,
    float* __restrict__ out)
{
  const int tid = threadIdx.x;
  const int w   = tid >> 6;          // 0: layer-0 wave, 1: layer-1 wave
  const int l   = tid & 63;
  const int m   = l >> 4;            // k-group; owns units 8m..8m+7
  const int col = l & 15;            // batch slot (16 batches/block)
  const int batch = blockIdx.x * 16 + col;

  __shared__ int ring[8][16 * LSTR];   // h0 ring, 8 steps deep (~10 KiB)

  // ---- weights: tile t row rho = gate(rho&3) of unit 8*(rho>>2)+t.
  //      Lane supplies A row = col. Pre-scaled: i,f,o -> -log2e; g -> +2log2e.
  const float* Bi  = (w == 0) ? bih0 : bih1;
  const float* Bh  = (w == 0) ? bhh0 : bhh1;
  const int   gcol = col & 3;              // gate type this lane's A-row feeds
  const float scA  = (gcol == 2) ? (2.0f * L2E) : (-L2E);
  const int   ub   = 8 * (col >> 2);       // A-row unit base

  bf16x8 wfA[8], wfB[8];   // w0: wfA=Whh0; w1: wfA=Wih1, wfB=Whh1
  f32x4  cb[8];            // MFMA C-in: per-slot gate bias (pre-scaled)
  float  w0x[8][4];        // w0 only: sc * Wih0 for owned units
  float  wfc[8];           // w1 only: FC weights
  #pragma unroll
  for (int t = 0; t < 8; ++t) {
    const int ga = gcol * 32 + ub + t;     // gate row in weight matrix
    #pragma unroll
    for (int j = 0; j < 8; ++j) {
      if (w == 0) {
        wfA[t][j] = f2bf(scA * Whh0[ga * HID + 8 * m + j]);
        wfB[t][j] = 0;
      } else {
        wfA[t][j] = f2bf(scA * Wih1[ga * HID + 8 * m + j]);
        wfB[t][j] = f2bf(scA * Whh1[ga * HID + 8 * m + j]);
      }
    }
    const int u = 8 * m + t;               // owned cell unit (tile t)
    #pragma unroll
    for (int r = 0; r < 4; ++r) {
      const float sc = (r == 2) ? (2.0f * L2E) : (-L2E);
      cb[t][r]  = sc * (Bi[r * 32 + u] + Bh[r * 32 + u]);
      w0x[t][r] = (w == 0) ? sc * Wih0[r * 32 + u] : 0.f;
    }
    wfc[t] = (w == 1) ? Wfc[u] : 0.f;
  }

  bf16x8 hf = {};                 // own h fragment (h0 for w0, h1 for w1)
  float cv[8], hh[8];
  #pragma unroll
  for (int t = 0; t < 8; ++t) { cv[t] = 0.f; hh[t] = 0.f; }

  const float* xb = x + (size_t)batch * SEQ;
  const int wrd = col * LSTR + 4 * m;      // ring b128 slot (dwords)

  float4 xcur = {0.f, 0.f, 0.f, 0.f};
  if (w == 0) xcur = *reinterpret_cast<const float4*>(xb);

  for (int k = 0; k <= SEQ / 4; ++k) {
    if (w == 0 && k < SEQ / 4) {
      // ---- producer: steps 4k..4k+3 of layer 0, all in-register ----
      float4 xnext = {0.f, 0.f, 0.f, 0.f};
      if (k + 1 < SEQ / 4)
        xnext = *reinterpret_cast<const float4*>(xb + (k + 1) * 4);
      #pragma unroll
      for (int uu = 0; uu < 4; ++uu) {
        const float xt = (uu == 0) ? xcur.x : (uu == 1) ? xcur.y
                       : (uu == 2) ? xcur.z : xcur.w;
        f32x4 A[8];
        #pragma unroll
        for (int t = 0; t < 8; ++t) {
          f32x4 cbx;
          #pragma unroll
          for (int r = 0; r < 4; ++r) cbx[r] = fmaf(w0x[t][r], xt, cb[t][r]);
          A[t] = __builtin_amdgcn_mfma_f32_16x16x32_bf16(wfA[t], hf, cbx, 0, 0, 0);
        }
        SCELL8(A);                  // staged ILP-8 activation
        i32x4 pk;
        #pragma unroll
        for (int j2 = 0; j2 < 4; ++j2) {
          int p;
          asm("v_cvt_pk_bf16_f32 %0, %1, %2"
              : "=v"(p) : "v"(hh[2 * j2]), "v"(hh[2 * j2 + 1]));
          pk[j2] = p;
        }
        hf = __builtin_bit_cast(bf16x8, pk);      // next-step B-frag, in-lane
        *(i32x4*)&ring[(4 * k + uu) & 7][wrd] = pk;  // publish h0 for w1
      }
      xcur = xnext;
    }
    if (w == 1 && k > 0) {
      // ---- consumer: steps 4(k-1)..4(k-1)+3 of layer 1 (lag 4..7) ----
      i32x4 h0v[4];
      #pragma unroll
      for (int uu = 0; uu < 4; ++uu)   // prefetch all 4 (written >=1 barrier ago)
        h0v[uu] = *(const i32x4*)&ring[(4 * (k - 1) + uu) & 7][wrd];
      #pragma unroll
      for (int uu = 0; uu < 4; ++uu) {
        const bf16x8 h0f = __builtin_bit_cast(bf16x8, h0v[uu]);
        f32x4 A[8];
        #pragma unroll
        for (int t = 0; t < 8; ++t)    // Wih1*h0 + bias (h1-independent, first)
          A[t] = __builtin_amdgcn_mfma_f32_16x16x32_bf16(wfA[t], h0f, cb[t], 0, 0, 0);
        #pragma unroll
        for (int t = 0; t < 8; ++t)    // + Whh1*h1 (fresh recurrent, last)
          A[t] = __builtin_amdgcn_mfma_f32_16x16x32_bf16(wfB[t], hf, A[t], 0, 0, 0);
        SCELL8(A);
        i32x4 pk;
        #pragma unroll
        for (int j2 = 0; j2 < 4; ++j2) {
          int p;
          asm("v_cvt_pk_bf16_f32 %0, %1, %2"
              : "=v"(p) : "v"(hh[2 * j2]), "v"(hh[2 * j2 + 1]));
          pk[j2] = p;
        }
        hf = __builtin_bit_cast(bf16x8, pk);      // h1 B-frag stays in-lane
      }
    }
    __syncthreads();   // one barrier per 4 steps (ring slots stay disjoint)
  }

  // ---- FC + ReLU: w1 holds h1(511) units 8m..8m+7 in hh ----
  if (w == 1) {
    float part = 0.f;
    #pragma unroll
    for (int t = 0; t < 8; ++t) part = fmaf(hh[t], wfc[t], part);
    part += __shfl_xor(part, 16);   // reduce over m (k-groups)
    part += __shfl_xor(part, 32);
    if (l < 16) {
      const float o = part + bfc[0];
      out[blockIdx.x * 16 + l] = o > 0.f ? o : 0.f;
    }
  }
}

extern "C" void kernel_launch(void* const* d_in, const int* in_sizes, int n_in,
                              void* d_out, int out_size, void* d_ws, size_t ws_size,
                              hipStream_t stream) {
  const float* x    = (const float*)d_in[0];
  const float* Wih0 = (const float*)d_in[1];
  const float* Whh0 = (const float*)d_in[2];
  const float* bih0 = (const float*)d_in[3];
  const float* bhh0 = (const float*)d_in[4];
  const float* Wih1 = (const float*)d_in[5];
  const float* Whh1 = (const float*)d_in[6];
  const float* bih1 = (const float*)d_in[7];
  const float* bhh1 = (const float*)d_in[8];
  const float* Wfc  = (const float*)d_in[9];
  const float* bfc  = (const float*)d_in[10];

  const int B = 4096;
  const int grid = B / 16;   // 256 blocks x 2 waves -> 1 block/CU
  lstm2_sa2_kernel<<<grid, 128, 0, stream>>>(
      x, Wih0, Whh0, bih0, bhh0, Wih1, Whh1, bih1, bhh1, Wfc, bfc,
      (float*)d_out);
}

// Round 22
// 272.202 us; speedup vs baseline: 1.3402x; 1.3402x over previous
//
#include <hip/hip_runtime.h>
#include <hip/hip_bf16.h>

// 2-layer LSTM (H=32, T=512, I=1) + FC(1) + ReLU, fused.
// ALL-REGISTER RECURRENCE AT 2 WAVES/SIMD -- synthesis of 21 rounds:
//   * self-aligned tile permutation (R18, verified): tile t row rho =
//     gate(rho&3) of unit 8*(rho>>2)+t => lane m's D rows of tile t are
//     (i,f,g,o) of unit 8m+t. Zero gate-type select.
//   * 4 batches/wave (cols = 4 replicas x 4 batches, col=4q+s): lane
//     (m,q,s) owns units {8m+2q, 8m+2q+1} of batch s -- 2 cells/lane,
//     64 distinct cells/wave. Own-tile select = 3 cndmask per f32x4.
//   * B-fragment reassembled IN-WAVE with DPP row_ror (R8's pack_bfrag,
//     proven): hd[J] = packed pair (4m+J) from lane col 4J+s. No LDS,
//     no swizzle, no barrier in either layer's recurrence chain.
//   * 8 waves/block = 4 L0-waves + 4 L1-waves (wave V handles batches
//     4V..4V+3). L0->L1 handoff via 8-deep LDS ring, 1 ds_write_b32 per
//     step, ONE __syncthreads per 4 steps. L1 lags 4..7 steps.
//   * MFMA per batch is 4x the R16 champion -- free at MfmaUtil 11%.
//   * merged-rcp CELL (7 trans); bias+x added post-MFMA for own cells
//     only (xc precomputed off-path). Grid 256 x 512 -> 2 waves/SIMD.

typedef __attribute__((ext_vector_type(8))) short bf16x8;
typedef __attribute__((ext_vector_type(4))) float f32x4;
typedef __attribute__((ext_vector_type(4))) int   i32x4;

#define HID 32
#define SEQ 512
#define NT4 (SEQ / 4)
#define L2E 1.4426950408889634f
#define LSTR 20   // ring row stride in dwords (16 used + 4 pad)

static __device__ __forceinline__ float fexp2(float x){ return __builtin_amdgcn_exp2f(x); }
static __device__ __forceinline__ float frcp (float x){ return __builtin_amdgcn_rcpf(x); }
static __device__ __forceinline__ short f2bf(float f){
  unsigned u = __builtin_bit_cast(unsigned, f);
  u = (u + 0x7fffu + ((u >> 16) & 1u)) >> 16;
  return (short)u;
}

// fused LSTM cell, merged-rcp form. Gates pre-scaled (i,f,o by -log2e;
// g by +2log2e):  I=e^-i, F=e^-f, O=e^-o, G=e^{2g}.
#define CELL(gi, gf, gg, go, cvr, hout) do {                         \
  const float I_ = fexp2(gi), G_ = fexp2(gg);                        \
  const float F_ = fexp2(gf), O_ = fexp2(go);                        \
  const float a_ = 1.f + I_, b_ = 1.f + G_, c_ = 1.f + F_;           \
  const float P1_ = a_ * b_;                                         \
  const float R_  = frcp(c_ * P1_);                                  \
  const float fv_ = P1_ * R_;                                        \
  const float ig_ = (G_ - 1.f) * (c_ * R_);                          \
  (cvr) = fmaf(fv_, (cvr), ig_);                                     \
  const float C2_ = fexp2((cvr) * (2.f * L2E));                      \
  (hout) = (C2_ - 1.f) * frcp((1.f + O_) * (1.f + C2_));             \
} while (0)

// B-frag from per-lane packed pair pk (pair 4m+q of batch s), col = 4q+s.
// hd[J] = pk of lane col 4J+s (same m,s). row_ror:i => dst n reads n-i.
// t_k (ror 4k) = replica (q-k)&3;  hd[J] = t_{(q-J)&3}.  (R8, verified)
static __device__ __forceinline__ i32x4 pack_bfrag(int pk, bool q1, bool q2) {
  const int t1 = __builtin_amdgcn_mov_dpp(pk, 0x124, 0xF, 0xF, false); // ror:4
  const int t2 = __builtin_amdgcn_mov_dpp(pk, 0x128, 0xF, 0xF, false); // ror:8
  const int t3 = __builtin_amdgcn_mov_dpp(pk, 0x12C, 0xF, 0xF, false); // ror:12
  const int u0 = q2 ? t2 : pk;
  const int u1 = q2 ? t1 : t3;
  const int u2 = q2 ? pk : t2;
  const int u3 = q2 ? t3 : t1;
  i32x4 hd;
  hd[0] = q1 ? u3 : u0;
  hd[1] = q1 ? u0 : u1;
  hd[2] = q1 ? u1 : u2;
  hd[3] = q1 ? u2 : u3;
  return hd;
}

// select own tile (2q+j) from A[8]: {j, 2+j, 4+j, 6+j} by (q1,q2)
#define SELT(A, j) ({                                 \
  const f32x4 lo_ = q1 ? A[2 + (j)] : A[(j)];         \
  const f32x4 hi_ = q1 ? A[6 + (j)] : A[4 + (j)];     \
  q2 ? hi_ : lo_; })

__global__ __launch_bounds__(512, 2) void lstm2_ar_kernel(
    const float* __restrict__ x,
    const float* __restrict__ Wih0, const float* __restrict__ Whh0,
    const float* __restrict__ bih0, const float* __restrict__ bhh0,
    const float* __restrict__ Wih1, const float* __restrict__ Whh1,
    const float* __restrict__ bih1, const float* __restrict__ bhh1,
    const float* __restrict__ Wfc, const float* __restrict__ bfc,
    float* __restrict__ out)
{
  const int tid = threadIdx.x;
  const int w   = tid >> 6;          // 0-3: L0 waves; 4-7: L1 waves
  const int l   = tid & 63;
  const int m   = l >> 4;            // k-group; D rows 4m..4m+3
  const int col = l & 15;            // MFMA col = 4q + s
  const int q   = col >> 2;          // replica -> owns units 8m+2q,+1
  const int s   = col & 3;           // batch slot within wave
  const int V   = w & 3;             // wave's batch group: 4V..4V+3
  const bool isL1 = (w >= 4);
  const bool q1 = (q & 1) != 0, q2 = (q & 2) != 0;
  const int batch = blockIdx.x * 16 + 4 * V + s;

  __shared__ int ring[8][16 * LSTR];   // h0 ring, 8 steps deep, 10 KiB

  // ---- weights, self-aligned permutation (A-row = col):
  //      row col of tile t = gate(col&3) of unit 8*(col>>2)+t.
  const int   gcol = col & 3;
  const float scA  = (gcol == 2) ? (2.0f * L2E) : (-L2E);
  const int   ub   = 8 * (col >> 2);
  const float* Wrec = isL1 ? Whh1 : Whh0;
  const float* Bi   = isL1 ? bih1 : bih0;
  const float* Bh   = isL1 ? bhh1 : bhh0;

  bf16x8 wfA[8], wfB[8];   // L0: wfA=Whh0 (wfB unused); L1: wfA=Wih1, wfB=Whh1
  #pragma unroll
  for (int t = 0; t < 8; ++t) {
    const int ga = gcol * 32 + ub + t;
    #pragma unroll
    for (int j = 0; j < 8; ++j) {
      if (!isL1) {
        wfA[t][j] = f2bf(scA * Wrec[ga * HID + 8 * m + j]);
        wfB[t][j] = 0;
      } else {
        wfA[t][j] = f2bf(scA * Wih1[ga * HID + 8 * m + j]);
        wfB[t][j] = f2bf(scA * Whh1[ga * HID + 8 * m + j]);
      }
    }
  }
  // per-lane constants for OWN 2 cells: units u_j = 8m + 2q + j
  float cb2[2][4], w0x[2][4], wfc2[2];
  #pragma unroll
  for (int j = 0; j < 2; ++j) {
    const int u = 8 * m + 2 * q + j;
    #pragma unroll
    for (int r = 0; r < 4; ++r) {
      const float sc = (r == 2) ? (2.0f * L2E) : (-L2E);
      cb2[j][r] = sc * (Bi[r * 32 + u] + Bh[r * 32 + u]);
      w0x[j][r] = isL1 ? 0.f : sc * Wih0[r * 32 + u];
    }
    wfc2[j] = isL1 ? Wfc[u] : 0.f;
  }

  bf16x8 hf = {};                    // own layer's h B-frag (in-register)
  float cv0 = 0.f, cv1 = 0.f, hn0 = 0.f, hn1 = 0.f;
  const f32x4 z4 = {0.f, 0.f, 0.f, 0.f};

  const float* xb = x + (size_t)batch * SEQ;
  const int wb = (4 * V + s) * LSTR + 4 * m + q;   // ring write dword
  const int rd = (4 * V + s) * LSTR + 4 * m;       // ring read b128

  float4 xcur = {0.f, 0.f, 0.f, 0.f};
  if (!isL1) xcur = *reinterpret_cast<const float4*>(xb);

  for (int k = 0; k <= NT4; ++k) {
    if (!isL1 && k < NT4) {
      // ---- L0: steps 4k..4k+3, recurrence fully in-register ----
      float4 xnext = {0.f, 0.f, 0.f, 0.f};
      if (k + 1 < NT4)
        xnext = *reinterpret_cast<const float4*>(xb + (k + 1) * 4);
      #pragma unroll
      for (int uu = 0; uu < 4; ++uu) {
        const float xt = (uu == 0) ? xcur.x : (uu == 1) ? xcur.y
                       : (uu == 2) ? xcur.z : xcur.w;
        float xc0[4], xc1[4];        // bias + x, off the MFMA path
        #pragma unroll
        for (int r = 0; r < 4; ++r) {
          xc0[r] = fmaf(w0x[0][r], xt, cb2[0][r]);
          xc1[r] = fmaf(w0x[1][r], xt, cb2[1][r]);
        }
        f32x4 A[8];
        #pragma unroll
        for (int t = 0; t < 8; ++t)
          A[t] = __builtin_amdgcn_mfma_f32_16x16x32_bf16(wfA[t], hf, z4, 0, 0, 0);
        const f32x4 A0 = SELT(A, 0), A1 = SELT(A, 1);
        CELL(A0[0] + xc0[0], A0[1] + xc0[1], A0[2] + xc0[2], A0[3] + xc0[3], cv0, hn0);
        CELL(A1[0] + xc1[0], A1[1] + xc1[1], A1[2] + xc1[2], A1[3] + xc1[3], cv1, hn1);
        int pk;
        asm("v_cvt_pk_bf16_f32 %0, %1, %2" : "=v"(pk) : "v"(hn0), "v"(hn1));
        hf = __builtin_bit_cast(bf16x8, pack_bfrag(pk, q1, q2));
        ring[(4 * k + uu) & 7][wb] = pk;     // publish h0 for L1
      }
      xcur = xnext;
    }
    if (isL1 && k > 0) {
      // ---- L1: steps 4(k-1)..4(k-1)+3 (lag 4..7), in-register h1 ----
      i32x4 h0v[4];
      #pragma unroll
      for (int uu = 0; uu < 4; ++uu)
        h0v[uu] = *(const i32x4*)&ring[(4 * (k - 1) + uu) & 7][rd];
      #pragma unroll
      for (int uu = 0; uu < 4; ++uu) {
        const bf16x8 h0f = __builtin_bit_cast(bf16x8, h0v[uu]);
        f32x4 A[8];
        #pragma unroll
        for (int t = 0; t < 8; ++t)    // Wih1*h0 first (h1-independent)
          A[t] = __builtin_amdgcn_mfma_f32_16x16x32_bf16(wfA[t], h0f, z4, 0, 0, 0);
        #pragma unroll
        for (int t = 0; t < 8; ++t)    // + Whh1*h1 (fresh recurrent, last)
          A[t] = __builtin_amdgcn_mfma_f32_16x16x32_bf16(wfB[t], hf, A[t], 0, 0, 0);
        const f32x4 A0 = SELT(A, 0), A1 = SELT(A, 1);
        CELL(A0[0] + cb2[0][0], A0[1] + cb2[0][1], A0[2] + cb2[0][2], A0[3] + cb2[0][3], cv0, hn0);
        CELL(A1[0] + cb2[1][0], A1[1] + cb2[1][1], A1[2] + cb2[1][2], A1[3] + cb2[1][3], cv1, hn1);
        int pk;
        asm("v_cvt_pk_bf16_f32 %0, %1, %2" : "=v"(pk) : "v"(hn0), "v"(hn1));
        hf = __builtin_bit_cast(bf16x8, pack_bfrag(pk, q1, q2));
      }
    }
    __syncthreads();   // one barrier per 4 steps (ring slots disjoint mod 8)
  }

  // ---- FC + ReLU: L1 lanes hold h1(511) of own 2 cells in hn0/hn1 ----
  if (isL1) {
    float part = hn0 * wfc2[0] + hn1 * wfc2[1];
    part += __shfl_xor(part, 4);    // reduce over q
    part += __shfl_xor(part, 8);
    part += __shfl_xor(part, 16);   // reduce over m
    part += __shfl_xor(part, 32);
    if (l < 4) {
      const float o = part + bfc[0];
      out[blockIdx.x * 16 + 4 * V + l] = o > 0.f ? o : 0.f;
    }
  }
}

extern "C" void kernel_launch(void* const* d_in, const int* in_sizes, int n_in,
                              void* d_out, int out_size, void* d_ws, size_t ws_size,
                              hipStream_t stream) {
  const float* x    = (const float*)d_in[0];
  const float* Wih0 = (const float*)d_in[1];
  const float* Whh0 = (const float*)d_in[2];
  const float* bih0 = (const float*)d_in[3];
  const float* bhh0 = (const float*)d_in[4];
  const float* Wih1 = (const float*)d_in[5];
  const float* Whh1 = (const float*)d_in[6];
  const float* bih1 = (const float*)d_in[7];
  const float* bhh1 = (const float*)d_in[8];
  const float* Wfc  = (const float*)d_in[9];
  const float* bfc  = (const float*)d_in[10];

  const int B = 4096;
  const int grid = B / 16;   // 256 blocks x 8 waves = 2048 waves -> 2/SIMD
  lstm2_ar_kernel<<<grid, 512, 0, stream>>>(
      x, Wih0, Whh0, bih0, bhh0, Wih1, Whh1, bih1, bhh1, Wfc, bfc,
      (float*)d_out);
}